// Round 1
// baseline (743.306 us; speedup 1.0000x reference)
//
#include <hip/hip_runtime.h>
#include <stdint.h>

// SNN pipeline: X[32768,1024] @ Wp^T -> LIF-ready h1; h1 @ Wh^T -> y2; LIF scan over T; pool; head.
// fp32 GEMMs emulated on bf16 matrix cores via hi/lo split (3 MFMA products), fp32 accumulate.

typedef short v8s __attribute__((ext_vector_type(8)));
typedef float v4f __attribute__((ext_vector_type(4)));

#define GAS __attribute__((address_space(1)))
#define LAS __attribute__((address_space(3)))

__device__ __forceinline__ unsigned short f2bf(float f) {
  unsigned int u = __float_as_uint(f);
  u += 0x7fffu + ((u >> 16) & 1u);   // round-to-nearest-even
  return (unsigned short)(u >> 16);
}
__device__ __forceinline__ float bf2f(unsigned short h) {
  return __uint_as_float(((unsigned int)h) << 16);
}

__device__ __forceinline__ void gld_lds16(const void* g, void* l) {
  __builtin_amdgcn_global_load_lds((const GAS void*)g, (LAS void*)l, 16, 0, 0);
}

// fp32 -> (bf16 hi, bf16 lo) elementwise split, float4-vectorized.
__global__ void __launch_bounds__(256) split_kernel(const float* __restrict__ in,
                                                    unsigned short* __restrict__ hi,
                                                    unsigned short* __restrict__ lo, int n4) {
  int i = blockIdx.x * 256 + threadIdx.x;
  if (i >= n4) return;
  float4 x = ((const float4*)in)[i];
  ushort4 h, l;
  h.x = f2bf(x.x); l.x = f2bf(x.x - bf2f(h.x));
  h.y = f2bf(x.y); l.y = f2bf(x.y - bf2f(h.y));
  h.z = f2bf(x.z); l.z = f2bf(x.z - bf2f(h.z));
  h.w = f2bf(x.w); l.w = f2bf(x.w - bf2f(h.w));
  ((ushort4*)hi)[i] = h;
  ((ushort4*)lo)[i] = l;
}

// C = A @ B^T with A[M,K], B[N,K] both split into bf16 hi/lo. K=N=1024 fixed.
// 128x128 tile, BK=32, 4 waves (2x2 of 64x64), 16x16x32 bf16 MFMA.
// MODE 0: out = bias-added result re-split to bf16 hi/lo (feeds next GEMM).
// MODE 1: out = bias-added fp32.
template <int MODE>
__global__ void __launch_bounds__(256, 2)
gemm_bt_split(const unsigned short* __restrict__ Ah, const unsigned short* __restrict__ Al,
              const unsigned short* __restrict__ Bh, const unsigned short* __restrict__ Bl,
              const float* __restrict__ bias,
              unsigned short* __restrict__ outH, unsigned short* __restrict__ outL,
              float* __restrict__ outF, int M) {
  constexpr int K = 1024, N = 1024;
  __shared__ unsigned short lA[2][128 * 32];  // [hi|lo] 8 KB each
  __shared__ unsigned short lB[2][128 * 32];

  const int tid = threadIdx.x;
  const int nt = blockIdx.x & 7;    // N/128 = 8
  const int mt = blockIdx.x >> 3;
  const int m0 = mt * 128, n0 = nt * 128;

  const int lane = tid & 63;
  const int wave = tid >> 6;
  const int wm = (wave >> 1) * 64, wn = (wave & 1) * 64;
  const int quad = lane >> 4, r = lane & 15;

  // staging: 256 threads x 16B = 4KB/issue = 64 rows; 2 issues per 8KB tile
  const int srow = tid >> 2;
  const int scol = (tid & 3) * 8;

  v4f acc[4][4];
#pragma unroll
  for (int i = 0; i < 4; ++i)
#pragma unroll
    for (int j = 0; j < 4; ++j) acc[i][j] = v4f{0.f, 0.f, 0.f, 0.f};

  const unsigned short* gAh = Ah + (size_t)(m0 + srow) * K + scol;
  const unsigned short* gAl = Al + (size_t)(m0 + srow) * K + scol;
  const unsigned short* gBh = Bh + (size_t)(n0 + srow) * K + scol;
  const unsigned short* gBl = Bl + (size_t)(n0 + srow) * K + scol;

  for (int kt = 0; kt < K; kt += 32) {
    gld_lds16(gAh + kt,          &lA[0][tid * 8]);
    gld_lds16(gAh + kt + 64 * K, &lA[0][tid * 8 + 64 * 32]);
    gld_lds16(gAl + kt,          &lA[1][tid * 8]);
    gld_lds16(gAl + kt + 64 * K, &lA[1][tid * 8 + 64 * 32]);
    gld_lds16(gBh + kt,          &lB[0][tid * 8]);
    gld_lds16(gBh + kt + 64 * K, &lB[0][tid * 8 + 64 * 32]);
    gld_lds16(gBl + kt,          &lB[1][tid * 8]);
    gld_lds16(gBl + kt + 64 * K, &lB[1][tid * 8 + 64 * 32]);
    __syncthreads();

    v8s ah[4], al[4], bh[4], bl[4];
#pragma unroll
    for (int i = 0; i < 4; ++i) {
      ah[i] = *(const v8s*)&lA[0][(wm + i * 16 + r) * 32 + quad * 8];
      al[i] = *(const v8s*)&lA[1][(wm + i * 16 + r) * 32 + quad * 8];
      bh[i] = *(const v8s*)&lB[0][(wn + i * 16 + r) * 32 + quad * 8];
      bl[i] = *(const v8s*)&lB[1][(wn + i * 16 + r) * 32 + quad * 8];
    }
#pragma unroll
    for (int i = 0; i < 4; ++i)
#pragma unroll
      for (int j = 0; j < 4; ++j) {
        acc[i][j] = __builtin_amdgcn_mfma_f32_16x16x32_bf16(ah[i], bh[j], acc[i][j], 0, 0, 0);
        acc[i][j] = __builtin_amdgcn_mfma_f32_16x16x32_bf16(ah[i], bl[j], acc[i][j], 0, 0, 0);
        acc[i][j] = __builtin_amdgcn_mfma_f32_16x16x32_bf16(al[i], bh[j], acc[i][j], 0, 0, 0);
      }
    __syncthreads();
  }

  // epilogue: C[m = quad*4+reg][n = lane&15] per verified gfx950 C/D layout
#pragma unroll
  for (int i = 0; i < 4; ++i)
#pragma unroll
    for (int j = 0; j < 4; ++j) {
      const int gn = n0 + wn + j * 16 + r;
      const float bv = bias[gn];
#pragma unroll
      for (int q2 = 0; q2 < 4; ++q2) {
        const int gm = m0 + wm + i * 16 + quad * 4 + q2;
        const float y = acc[i][j][q2] + bv;
        const size_t o = (size_t)gm * N + gn;
        if (MODE == 0) {
          unsigned short h = f2bf(y);
          unsigned short l = f2bf(y - bf2f(h));
          outH[o] = h;
          outL[o] = l;
        } else {
          outF[o] = y;
        }
      }
    }
}

// LIF scan + time-mean pool. One thread per (b,h) channel; 16-deep load batch for MLP.
__global__ void __launch_bounds__(256) lif_pool_kernel(const float* __restrict__ y2,
                                                       float* __restrict__ pooled) {
  int idx = blockIdx.x * 256 + threadIdx.x;  // b*1024 + h
  const float* p = y2 + ((size_t)(idx >> 10) << 20) + (idx & 1023);
  float v = 0.f, cnt = 0.f;
  for (int t0 = 0; t0 < 1024; t0 += 16) {
    float x[16];
#pragma unroll
    for (int i = 0; i < 16; ++i) x[i] = p[(size_t)(t0 + i) * 1024];
#pragma unroll
    for (int i = 0; i < 16; ++i) {
      v += (x[i] - v) * 0.5f;              // exact reference op order
      float s = (v >= 1.0f) ? 1.0f : 0.0f;
      cnt += s;
      v -= s;
    }
  }
  pooled[idx] = cnt * (1.0f / 1024.0f);    // /1024 exact
}

// out[b,o] = pooled[b,:] . W_out[o,:] + b_out[o]; one wave per output.
__global__ void __launch_bounds__(64) head_kernel(const float* __restrict__ pooled,
                                                  const float* __restrict__ W_out,
                                                  const float* __restrict__ b_out,
                                                  float* __restrict__ out) {
  int blk = blockIdx.x;          // 0..319
  int b = blk / 10, o = blk % 10;
  int lane = threadIdx.x;
  const float* pr = pooled + b * 1024;
  const float* wr = W_out + o * 1024;
  float s = 0.f;
#pragma unroll
  for (int i = 0; i < 16; ++i) s += pr[lane + 64 * i] * wr[lane + 64 * i];
#pragma unroll
  for (int off = 32; off > 0; off >>= 1) s += __shfl_down(s, off);
  if (lane == 0) out[b * 10 + o] = s + b_out[o];
}

extern "C" void kernel_launch(void* const* d_in, const int* in_sizes, int n_in,
                              void* d_out, int out_size, void* d_ws, size_t ws_size,
                              hipStream_t stream) {
  const float* x      = (const float*)d_in[0];
  const float* W_proj = (const float*)d_in[1];
  const float* b_proj = (const float*)d_in[2];
  const float* W_hid  = (const float*)d_in[3];
  const float* b_hid  = (const float*)d_in[4];
  const float* W_out  = (const float*)d_in[5];
  const float* b_out  = (const float*)d_in[6];
  float* out = (float*)d_out;

  const int M = 32768;                    // B*T
  const size_t nX = (size_t)M * 1024;     // 33554432
  const size_t nW = (size_t)1024 * 1024;  // 1048576

  // Workspace layout (~277 MB). Y2 (fp32) aliases the X hi/lo region: X splits
  // are dead after GEMM1, and GEMM2 reads only Y1h/Y1l + Wh splits.
  char* ws = (char*)d_ws;
  unsigned short* Xh  = (unsigned short*)(ws);
  unsigned short* Xl  = (unsigned short*)(ws + 67108864);
  float*          Y2  = (float*)(ws);                       // 134217728 B, aliases Xh+Xl
  unsigned short* Y1h = (unsigned short*)(ws + 134217728);
  unsigned short* Y1l = (unsigned short*)(ws + 201326592);
  unsigned short* Wph = (unsigned short*)(ws + 268435456);
  unsigned short* Wpl = (unsigned short*)(ws + 268435456 + 2097152);
  unsigned short* Whh = (unsigned short*)(ws + 268435456 + 4194304);
  unsigned short* Whl = (unsigned short*)(ws + 268435456 + 6291456);
  float*       pooled = (float*)(ws + 268435456 + 8388608);

  split_kernel<<<(int)(nX / 4 / 256), 256, 0, stream>>>(x, Xh, Xl, (int)(nX / 4));
  split_kernel<<<(int)(nW / 4 / 256), 256, 0, stream>>>(W_proj, Wph, Wpl, (int)(nW / 4));
  split_kernel<<<(int)(nW / 4 / 256), 256, 0, stream>>>(W_hid, Whh, Whl, (int)(nW / 4));

  gemm_bt_split<0><<<2048, 256, 0, stream>>>(Xh, Xl, Wph, Wpl, b_proj, Y1h, Y1l, nullptr, M);
  gemm_bt_split<1><<<2048, 256, 0, stream>>>(Y1h, Y1l, Whh, Whl, b_hid, nullptr, nullptr, Y2, M);

  lif_pool_kernel<<<128, 256, 0, stream>>>(Y2, pooled);
  head_kernel<<<320, 64, 0, stream>>>(pooled, W_out, b_out, out);
}

// Round 2
// 525.976 us; speedup vs baseline: 1.4132x; 1.4132x over previous
//
#include <hip/hip_runtime.h>
#include <stdint.h>

// SNN pipeline, algebraically fused: y2 = x @ (Wh@Wp)^T + (Wh@bp + bh), then
// LIF scan over T, time-mean pool, tiny head. fp32 GEMM emulated on bf16
// matrix cores via hi/lo split (3 MFMA products), fp32 accumulate.

typedef short v8s __attribute__((ext_vector_type(8)));
typedef float v4f __attribute__((ext_vector_type(4)));

#define GAS __attribute__((address_space(1)))
#define LAS __attribute__((address_space(3)))

__device__ __forceinline__ unsigned short f2bf(float f) {
  unsigned int u = __float_as_uint(f);
  u += 0x7fffu + ((u >> 16) & 1u);   // round-to-nearest-even
  return (unsigned short)(u >> 16);
}
__device__ __forceinline__ float bf2f(unsigned short h) {
  return __uint_as_float(((unsigned int)h) << 16);
}

__device__ __forceinline__ void gld_lds16(const void* g, void* l) {
  __builtin_amdgcn_global_load_lds((const GAS void*)g, (LAS void*)l, 16, 0, 0);
}

// fp32 -> (bf16 hi, bf16 lo) elementwise split, float4-vectorized.
__global__ void __launch_bounds__(256) split_kernel(const float* __restrict__ in,
                                                    unsigned short* __restrict__ hi,
                                                    unsigned short* __restrict__ lo, int n4) {
  int i = blockIdx.x * 256 + threadIdx.x;
  if (i >= n4) return;
  float4 x = ((const float4*)in)[i];
  ushort4 h, l;
  h.x = f2bf(x.x); l.x = f2bf(x.x - bf2f(h.x));
  h.y = f2bf(x.y); l.y = f2bf(x.y - bf2f(h.y));
  h.z = f2bf(x.z); l.z = f2bf(x.z - bf2f(h.z));
  h.w = f2bf(x.w); l.w = f2bf(x.w - bf2f(h.w));
  ((ushort4*)hi)[i] = h;
  ((ushort4*)lo)[i] = l;
}

// outT[d,h] = in[h,d] for 1024x1024 fp32, split to bf16 hi/lo. LDS 32x32 tile.
__global__ void __launch_bounds__(256) transpose_split(const float* __restrict__ in,
                                                       unsigned short* __restrict__ hiT,
                                                       unsigned short* __restrict__ loT) {
  __shared__ float t[32][33];
  const int tx = threadIdx.x & 31, ty = threadIdx.x >> 5;  // 32x8
  const int x = blockIdx.x * 32 + tx;
  const int yb = blockIdx.y * 32;
#pragma unroll
  for (int j = 0; j < 4; ++j) t[ty + 8 * j][tx] = in[(size_t)(yb + ty + 8 * j) * 1024 + x];
  __syncthreads();
  const int xo = yb + tx;
#pragma unroll
  for (int j = 0; j < 4; ++j) {
    const float v = t[tx][ty + 8 * j];
    const unsigned short h = f2bf(v);
    const size_t o = (size_t)(blockIdx.x * 32 + ty + 8 * j) * 1024 + xo;
    hiT[o] = h;
    loT[o] = f2bf(v - bf2f(h));
  }
}

// bc[g] = dot(Wh[g,:], bp) + bh[g]; one wave per g.
__global__ void __launch_bounds__(64) bias_combine(const float* __restrict__ Wh,
                                                   const float* __restrict__ bp,
                                                   const float* __restrict__ bh,
                                                   float* __restrict__ bc) {
  const int g = blockIdx.x, lane = threadIdx.x;
  const float* wr = Wh + (size_t)g * 1024;
  float s = 0.f;
#pragma unroll
  for (int i = 0; i < 16; ++i) s += wr[lane + 64 * i] * bp[lane + 64 * i];
#pragma unroll
  for (int off = 32; off > 0; off >>= 1) s += __shfl_down(s, off);
  if (lane == 0) bc[g] = s + bh[g];
}

// C = A @ B^T + bias, A[M,K], B[N,K] split into bf16 hi/lo; K=N=1024 fixed.
// 128x128 tile, BK=32, 4 waves (2x2 of 64x64), 16x16x32 bf16 MFMA, 3 products.
// Block swizzle keeps the 8 blocks sharing an A-tile on one XCD (blk%8).
__global__ void __launch_bounds__(256, 2)
gemm_bt_split(const unsigned short* __restrict__ Ah, const unsigned short* __restrict__ Al,
              const unsigned short* __restrict__ Bh, const unsigned short* __restrict__ Bl,
              const float* __restrict__ bias, float* __restrict__ outF, int M) {
  constexpr int K = 1024, N = 1024;
  __shared__ unsigned short lA[2][128 * 32];  // [hi|lo] 8 KB each
  __shared__ unsigned short lB[2][128 * 32];

  const int tid = threadIdx.x;
  // XCD-aware swizzle: c = XCD (round-robin heuristic), band of mt per XCD.
  const int mt_total = M >> 7;
  const int band = mt_total >> 3;            // 32 for M=32768, 1 for M=1024
  const int c = blockIdx.x & 7;
  const int idx = blockIdx.x >> 3;
  const int mt = c * band + (idx >> 3);
  const int nt = idx & 7;
  const int m0 = mt * 128, n0 = nt * 128;

  const int lane = tid & 63;
  const int wave = tid >> 6;
  const int wm = (wave >> 1) * 64, wn = (wave & 1) * 64;
  const int quad = lane >> 4, r = lane & 15;

  const int srow = tid >> 2;
  const int scol = (tid & 3) * 8;

  v4f acc[4][4];
#pragma unroll
  for (int i = 0; i < 4; ++i)
#pragma unroll
    for (int j = 0; j < 4; ++j) acc[i][j] = v4f{0.f, 0.f, 0.f, 0.f};

  const unsigned short* gAh = Ah + (size_t)(m0 + srow) * K + scol;
  const unsigned short* gAl = Al + (size_t)(m0 + srow) * K + scol;
  const unsigned short* gBh = Bh + (size_t)(n0 + srow) * K + scol;
  const unsigned short* gBl = Bl + (size_t)(n0 + srow) * K + scol;

  for (int kt = 0; kt < K; kt += 32) {
    gld_lds16(gAh + kt,          &lA[0][tid * 8]);
    gld_lds16(gAh + kt + 64 * K, &lA[0][tid * 8 + 64 * 32]);
    gld_lds16(gAl + kt,          &lA[1][tid * 8]);
    gld_lds16(gAl + kt + 64 * K, &lA[1][tid * 8 + 64 * 32]);
    gld_lds16(gBh + kt,          &lB[0][tid * 8]);
    gld_lds16(gBh + kt + 64 * K, &lB[0][tid * 8 + 64 * 32]);
    gld_lds16(gBl + kt,          &lB[1][tid * 8]);
    gld_lds16(gBl + kt + 64 * K, &lB[1][tid * 8 + 64 * 32]);
    __syncthreads();

    v8s ah[4], al[4], bh[4], bl[4];
#pragma unroll
    for (int i = 0; i < 4; ++i) {
      ah[i] = *(const v8s*)&lA[0][(wm + i * 16 + r) * 32 + quad * 8];
      al[i] = *(const v8s*)&lA[1][(wm + i * 16 + r) * 32 + quad * 8];
      bh[i] = *(const v8s*)&lB[0][(wn + i * 16 + r) * 32 + quad * 8];
      bl[i] = *(const v8s*)&lB[1][(wn + i * 16 + r) * 32 + quad * 8];
    }
#pragma unroll
    for (int i = 0; i < 4; ++i)
#pragma unroll
      for (int j = 0; j < 4; ++j) {
        acc[i][j] = __builtin_amdgcn_mfma_f32_16x16x32_bf16(ah[i], bh[j], acc[i][j], 0, 0, 0);
        acc[i][j] = __builtin_amdgcn_mfma_f32_16x16x32_bf16(ah[i], bl[j], acc[i][j], 0, 0, 0);
        acc[i][j] = __builtin_amdgcn_mfma_f32_16x16x32_bf16(al[i], bh[j], acc[i][j], 0, 0, 0);
      }
    __syncthreads();
  }

  // epilogue: C[m = quad*4+reg][n = lane&15] per verified gfx950 C/D layout
#pragma unroll
  for (int i = 0; i < 4; ++i)
#pragma unroll
    for (int j = 0; j < 4; ++j) {
      const int gn = n0 + wn + j * 16 + r;
      const float bv = bias ? bias[gn] : 0.f;
#pragma unroll
      for (int q2 = 0; q2 < 4; ++q2) {
        const int gm = m0 + wm + i * 16 + quad * 4 + q2;
        outF[(size_t)gm * N + gn] = acc[i][j][q2] + bv;
      }
    }
}

// LIF scan + time-mean pool. One thread per (b,h) channel; 16-deep load batch.
__global__ void __launch_bounds__(128) lif_pool_kernel(const float* __restrict__ y2,
                                                       float* __restrict__ pooled) {
  int idx = blockIdx.x * 128 + threadIdx.x;  // b*1024 + h
  const float* p = y2 + ((size_t)(idx >> 10) << 20) + (idx & 1023);
  float v = 0.f, cnt = 0.f;
  for (int t0 = 0; t0 < 1024; t0 += 16) {
    float x[16];
#pragma unroll
    for (int i = 0; i < 16; ++i) x[i] = p[(size_t)(t0 + i) * 1024];
#pragma unroll
    for (int i = 0; i < 16; ++i) {
      v += (x[i] - v) * 0.5f;              // exact reference op order
      float s = (v >= 1.0f) ? 1.0f : 0.0f;
      cnt += s;
      v -= s;
    }
  }
  pooled[idx] = cnt * (1.0f / 1024.0f);
}

// out[b,o] = pooled[b,:] . W_out[o,:] + b_out[o]; one wave per output.
__global__ void __launch_bounds__(64) head_kernel(const float* __restrict__ pooled,
                                                  const float* __restrict__ W_out,
                                                  const float* __restrict__ b_out,
                                                  float* __restrict__ out) {
  int blk = blockIdx.x;          // 0..319
  int b = blk / 10, o = blk % 10;
  int lane = threadIdx.x;
  const float* pr = pooled + b * 1024;
  const float* wr = W_out + o * 1024;
  float s = 0.f;
#pragma unroll
  for (int i = 0; i < 16; ++i) s += pr[lane + 64 * i] * wr[lane + 64 * i];
#pragma unroll
  for (int off = 32; off > 0; off >>= 1) s += __shfl_down(s, off);
  if (lane == 0) out[b * 10 + o] = s + b_out[o];
}

extern "C" void kernel_launch(void* const* d_in, const int* in_sizes, int n_in,
                              void* d_out, int out_size, void* d_ws, size_t ws_size,
                              hipStream_t stream) {
  const float* x      = (const float*)d_in[0];
  const float* W_proj = (const float*)d_in[1];
  const float* b_proj = (const float*)d_in[2];
  const float* W_hid  = (const float*)d_in[3];
  const float* b_hid  = (const float*)d_in[4];
  const float* W_out  = (const float*)d_in[5];
  const float* b_out  = (const float*)d_in[6];
  float* out = (float*)d_out;

  const int M = 32768;                    // B*T
  const size_t nX = (size_t)M * 1024;
  const size_t nW = (size_t)1024 * 1024;

  // Workspace (~277 MB):
  //   [0, 64M)        Xh
  //   [64M, 128M)     Xl
  //   [128M, 256M)    Y2 fp32 (Wc fp32 temporarily lives at its start; dead
  //                   once split, before the big GEMM writes Y2)
  //   [256M, ...)     WpT/Wc hi+lo (aliased), Wh hi/lo, pooled, bc
  char* ws = (char*)d_ws;
  unsigned short* Xh   = (unsigned short*)(ws);
  unsigned short* Xl   = (unsigned short*)(ws + 67108864);
  float*          Y2   = (float*)(ws + 134217728);
  float*          Wc   = (float*)(ws + 134217728);          // aliases Y2 start
  char* base = ws + 268435456;
  unsigned short* WpTh = (unsigned short*)(base);            // later reused as Wch
  unsigned short* WpTl = (unsigned short*)(base + 2097152);  // later reused as Wcl
  unsigned short* Whh  = (unsigned short*)(base + 4194304);
  unsigned short* Whl  = (unsigned short*)(base + 6291456);
  float*       pooled  = (float*)(base + 8388608);
  float*           bc  = (float*)(base + 8388608 + 131072);
  unsigned short* Wch  = WpTh;  // WpT dead after Wc GEMM
  unsigned short* Wcl  = WpTl;

  // Small-weight preprocessing
  transpose_split<<<dim3(32, 32), 256, 0, stream>>>(W_proj, WpTh, WpTl);
  split_kernel<<<(int)(nW / 4 / 256), 256, 0, stream>>>(W_hid, Whh, Whl, (int)(nW / 4));
  bias_combine<<<1024, 64, 0, stream>>>(W_hid, b_proj, b_hid, bc);
  // Wc[g,d] = sum_h Wh[g,h] * WpT[d,h]
  gemm_bt_split<<<64, 256, 0, stream>>>(Whh, Whl, WpTh, WpTl, nullptr, Wc, 1024);
  split_kernel<<<(int)(nW / 4 / 256), 256, 0, stream>>>(Wc, Wch, Wcl, (int)(nW / 4));

  // Main path
  split_kernel<<<(int)(nX / 4 / 256), 256, 0, stream>>>(x, Xh, Xl, (int)(nX / 4));
  gemm_bt_split<<<2048, 256, 0, stream>>>(Xh, Xl, Wch, Wcl, bc, Y2, M);

  lif_pool_kernel<<<256, 128, 0, stream>>>(Y2, pooled);
  head_kernel<<<320, 64, 0, stream>>>(pooled, W_out, b_out, out);
}

// Round 3
// 502.352 us; speedup vs baseline: 1.4797x; 1.0470x over previous
//
#include <hip/hip_runtime.h>
#include <stdint.h>

// SNN pipeline, algebraically fused: y2 = x @ (Wh@Wp)^T + (Wh@bp + bh), then
// T-parallel LIF scan (shadowing warm-up), time-mean pool, tiny head.
// fp32 GEMM emulated on bf16 matrix cores via hi/lo split (3 MFMA products).

typedef short v8s __attribute__((ext_vector_type(8)));
typedef float v16f __attribute__((ext_vector_type(16)));

#define GAS __attribute__((address_space(1)))
#define LAS __attribute__((address_space(3)))

__device__ __forceinline__ unsigned short f2bf(float f) {
  unsigned int u = __float_as_uint(f);
  u += 0x7fffu + ((u >> 16) & 1u);   // round-to-nearest-even
  return (unsigned short)(u >> 16);
}
__device__ __forceinline__ float bf2f(unsigned short h) {
  return __uint_as_float(((unsigned int)h) << 16);
}

__device__ __forceinline__ void gld_lds16(const void* g, void* l) {
  __builtin_amdgcn_global_load_lds((const GAS void*)g, (LAS void*)l, 16, 0, 0);
}

// fp32 -> (bf16 hi, bf16 lo) elementwise split, float4-vectorized.
__global__ void __launch_bounds__(256) split_kernel(const float* __restrict__ in,
                                                    unsigned short* __restrict__ hi,
                                                    unsigned short* __restrict__ lo, int n4) {
  int i = blockIdx.x * 256 + threadIdx.x;
  if (i >= n4) return;
  float4 x = ((const float4*)in)[i];
  ushort4 h, l;
  h.x = f2bf(x.x); l.x = f2bf(x.x - bf2f(h.x));
  h.y = f2bf(x.y); l.y = f2bf(x.y - bf2f(h.y));
  h.z = f2bf(x.z); l.z = f2bf(x.z - bf2f(h.z));
  h.w = f2bf(x.w); l.w = f2bf(x.w - bf2f(h.w));
  ((ushort4*)hi)[i] = h;
  ((ushort4*)lo)[i] = l;
}

// outT[d,h] = in[h,d] for 1024x1024 fp32, split to bf16 hi/lo. LDS 32x32 tile.
__global__ void __launch_bounds__(256) transpose_split(const float* __restrict__ in,
                                                       unsigned short* __restrict__ hiT,
                                                       unsigned short* __restrict__ loT) {
  __shared__ float t[32][33];
  const int tx = threadIdx.x & 31, ty = threadIdx.x >> 5;  // 32x8
  const int x = blockIdx.x * 32 + tx;
  const int yb = blockIdx.y * 32;
#pragma unroll
  for (int j = 0; j < 4; ++j) t[ty + 8 * j][tx] = in[(size_t)(yb + ty + 8 * j) * 1024 + x];
  __syncthreads();
  const int xo = yb + tx;
#pragma unroll
  for (int j = 0; j < 4; ++j) {
    const float v = t[tx][ty + 8 * j];
    const unsigned short h = f2bf(v);
    const size_t o = (size_t)(blockIdx.x * 32 + ty + 8 * j) * 1024 + xo;
    hiT[o] = h;
    loT[o] = f2bf(v - bf2f(h));
  }
}

// bc[g] = dot(Wh[g,:], bp) + bh[g]; one wave per g.
__global__ void __launch_bounds__(64) bias_combine(const float* __restrict__ Wh,
                                                   const float* __restrict__ bp,
                                                   const float* __restrict__ bh,
                                                   float* __restrict__ bc) {
  const int g = blockIdx.x, lane = threadIdx.x;
  const float* wr = Wh + (size_t)g * 1024;
  float s = 0.f;
#pragma unroll
  for (int i = 0; i < 16; ++i) s += wr[lane + 64 * i] * bp[lane + 64 * i];
#pragma unroll
  for (int off = 32; off > 0; off >>= 1) s += __shfl_down(s, off);
  if (lane == 0) bc[g] = s + bh[g];
}

// C = A @ B^T + bias, A[M,K], B[N,K] split into bf16 hi/lo; K=N=1024 fixed.
// 128x128 tile, BK=32, 4 waves (2x2 of 64x64), 32x32x16 bf16 MFMA, 3 products.
// Block swizzle keeps the 8 blocks sharing an A-tile on one XCD (blk%8).
__global__ void __launch_bounds__(256, 2)
gemm_bt_split(const unsigned short* __restrict__ Ah, const unsigned short* __restrict__ Al,
              const unsigned short* __restrict__ Bh, const unsigned short* __restrict__ Bl,
              const float* __restrict__ bias, float* __restrict__ outF, int M) {
  constexpr int K = 1024, N = 1024;
  __shared__ unsigned short lA[2][128 * 32];  // [hi|lo] 8 KB each
  __shared__ unsigned short lB[2][128 * 32];

  const int tid = threadIdx.x;
  const int mt_total = M >> 7;
  const int band = mt_total >> 3;            // 32 for M=32768, 1 for M=1024
  const int c = blockIdx.x & 7;
  const int idx = blockIdx.x >> 3;
  const int mt = c * band + (idx >> 3);
  const int nt = idx & 7;
  const int m0 = mt * 128, n0 = nt * 128;

  const int lane = tid & 63;
  const int wave = tid >> 6;
  const int wm = (wave >> 1) * 64, wn = (wave & 1) * 64;
  const int ln31 = lane & 31, lh = lane >> 5;

  const int srow = tid >> 2;
  const int scol = (tid & 3) * 8;

  v16f acc[2][2];
#pragma unroll
  for (int i = 0; i < 2; ++i)
#pragma unroll
    for (int j = 0; j < 2; ++j)
#pragma unroll
      for (int e = 0; e < 16; ++e) acc[i][j][e] = 0.f;

  const unsigned short* gAh = Ah + (size_t)(m0 + srow) * K + scol;
  const unsigned short* gAl = Al + (size_t)(m0 + srow) * K + scol;
  const unsigned short* gBh = Bh + (size_t)(n0 + srow) * K + scol;
  const unsigned short* gBl = Bl + (size_t)(n0 + srow) * K + scol;

  for (int kt = 0; kt < K; kt += 32) {
    gld_lds16(gAh + kt,          &lA[0][tid * 8]);
    gld_lds16(gAh + kt + 64 * K, &lA[0][tid * 8 + 64 * 32]);
    gld_lds16(gAl + kt,          &lA[1][tid * 8]);
    gld_lds16(gAl + kt + 64 * K, &lA[1][tid * 8 + 64 * 32]);
    gld_lds16(gBh + kt,          &lB[0][tid * 8]);
    gld_lds16(gBh + kt + 64 * K, &lB[0][tid * 8 + 64 * 32]);
    gld_lds16(gBl + kt,          &lB[1][tid * 8]);
    gld_lds16(gBl + kt + 64 * K, &lB[1][tid * 8 + 64 * 32]);
    __syncthreads();

    // frags: A[m=lane&31][k=(lane>>5)*8+j], two k-steps (s) of 16 per BK=32
    v8s ah[2][2], al[2][2], bh[2][2], bl[2][2];  // [i or j][s]
#pragma unroll
    for (int i = 0; i < 2; ++i)
#pragma unroll
      for (int s = 0; s < 2; ++s) {
        const int ra = (wm + i * 32 + ln31) * 32 + s * 16 + lh * 8;
        const int rb = (wn + i * 32 + ln31) * 32 + s * 16 + lh * 8;
        ah[i][s] = *(const v8s*)&lA[0][ra];
        al[i][s] = *(const v8s*)&lA[1][ra];
        bh[i][s] = *(const v8s*)&lB[0][rb];
        bl[i][s] = *(const v8s*)&lB[1][rb];
      }
#pragma unroll
    for (int s = 0; s < 2; ++s) {
#pragma unroll
      for (int i = 0; i < 2; ++i)
#pragma unroll
        for (int j = 0; j < 2; ++j)
          acc[i][j] = __builtin_amdgcn_mfma_f32_32x32x16_bf16(ah[i][s], bh[j][s], acc[i][j], 0, 0, 0);
#pragma unroll
      for (int i = 0; i < 2; ++i)
#pragma unroll
        for (int j = 0; j < 2; ++j)
          acc[i][j] = __builtin_amdgcn_mfma_f32_32x32x16_bf16(ah[i][s], bl[j][s], acc[i][j], 0, 0, 0);
#pragma unroll
      for (int i = 0; i < 2; ++i)
#pragma unroll
        for (int j = 0; j < 2; ++j)
          acc[i][j] = __builtin_amdgcn_mfma_f32_32x32x16_bf16(al[i][s], bh[j][s], acc[i][j], 0, 0, 0);
    }
    __syncthreads();
  }

  // epilogue: 32x32 C/D layout: col=lane&31, row=(reg&3)+8*(reg>>2)+4*(lane>>5)
#pragma unroll
  for (int i = 0; i < 2; ++i)
#pragma unroll
    for (int j = 0; j < 2; ++j) {
      const int gn = n0 + wn + j * 32 + ln31;
      const float bv = bias ? bias[gn] : 0.f;
#pragma unroll
      for (int reg = 0; reg < 16; ++reg) {
        const int gm = m0 + wm + i * 32 + (reg & 3) + 8 * (reg >> 2) + 4 * lh;
        outF[(size_t)gm * N + gn] = acc[i][j][reg] + bv;
      }
    }
}

// T-parallel LIF: 8 chunks of 128 steps, 64-step shadowing warm-up (state
// contracts x0.5/step -> bit-exact convergence before the chunk starts).
__global__ void __launch_bounds__(256) lif_part_kernel(const float* __restrict__ y2,
                                                       float* __restrict__ part) {
  const int idx = blockIdx.x * 256 + threadIdx.x;  // chunk*32768 + ch
  const int ch = idx & 32767, chunk = idx >> 15;
  const float* p = y2 + ((size_t)(ch >> 10) << 20) + (ch & 1023);
  const int t0 = chunk << 7;
  float v = 0.f;
  if (chunk) {  // uniform per wave (32768 % 64 == 0)
    const float* pw = p + (size_t)(t0 - 64) * 1024;
    for (int b = 0; b < 64; b += 16) {
      float x[16];
#pragma unroll
      for (int i = 0; i < 16; ++i) x[i] = pw[(size_t)(b + i) * 1024];
#pragma unroll
      for (int i = 0; i < 16; ++i) {
        v += (x[i] - v) * 0.5f;
        if (v >= 1.0f) v -= 1.0f;          // same arithmetic as spike branch
      }
    }
  }
  float cnt = 0.f;
  const float* pm = p + (size_t)t0 * 1024;
  for (int b = 0; b < 128; b += 16) {
    float x[16];
#pragma unroll
    for (int i = 0; i < 16; ++i) x[i] = pm[(size_t)(b + i) * 1024];
#pragma unroll
    for (int i = 0; i < 16; ++i) {
      v += (x[i] - v) * 0.5f;              // exact reference op order
      float s = (v >= 1.0f) ? 1.0f : 0.0f;
      cnt += s;
      v -= s;
    }
  }
  part[idx] = cnt;
}

// pooled[ch] = sum_c part[c][ch] / 1024   (integer counts -> any order exact)
__global__ void __launch_bounds__(256) pool_reduce(const float* __restrict__ part,
                                                   float* __restrict__ pooled) {
  const int i = blockIdx.x * 256 + threadIdx.x;  // 32768
  float s = 0.f;
#pragma unroll
  for (int c = 0; c < 8; ++c) s += part[c * 32768 + i];
  pooled[i] = s * (1.0f / 1024.0f);
}

// out[b,o] = pooled[b,:] . W_out[o,:] + b_out[o]; one wave per output.
__global__ void __launch_bounds__(64) head_kernel(const float* __restrict__ pooled,
                                                  const float* __restrict__ W_out,
                                                  const float* __restrict__ b_out,
                                                  float* __restrict__ out) {
  int blk = blockIdx.x;          // 0..319
  int b = blk / 10, o = blk % 10;
  int lane = threadIdx.x;
  const float* pr = pooled + b * 1024;
  const float* wr = W_out + o * 1024;
  float s = 0.f;
#pragma unroll
  for (int i = 0; i < 16; ++i) s += pr[lane + 64 * i] * wr[lane + 64 * i];
#pragma unroll
  for (int off = 32; off > 0; off >>= 1) s += __shfl_down(s, off);
  if (lane == 0) out[b * 10 + o] = s + b_out[o];
}

extern "C" void kernel_launch(void* const* d_in, const int* in_sizes, int n_in,
                              void* d_out, int out_size, void* d_ws, size_t ws_size,
                              hipStream_t stream) {
  const float* x      = (const float*)d_in[0];
  const float* W_proj = (const float*)d_in[1];
  const float* b_proj = (const float*)d_in[2];
  const float* W_hid  = (const float*)d_in[3];
  const float* b_hid  = (const float*)d_in[4];
  const float* W_out  = (const float*)d_in[5];
  const float* b_out  = (const float*)d_in[6];
  float* out = (float*)d_out;

  const int M = 32768;                    // B*T
  const size_t nX = (size_t)M * 1024;
  const size_t nW = (size_t)1024 * 1024;

  // Workspace (~277 MB):
  //   [0, 64M)        Xh   (dead after big GEMM; `part` aliases its start)
  //   [64M, 128M)     Xl
  //   [128M, 256M)    Y2 fp32 (Wc fp32 temporarily at its start; dead once split)
  //   [256M, ...)     WpT/Wc hi+lo (aliased), Wh hi/lo, pooled, bc
  char* ws = (char*)d_ws;
  unsigned short* Xh   = (unsigned short*)(ws);
  unsigned short* Xl   = (unsigned short*)(ws + 67108864);
  float*          part = (float*)(ws);                      // 1 MB, aliases Xh
  float*          Y2   = (float*)(ws + 134217728);
  float*          Wc   = (float*)(ws + 134217728);          // aliases Y2 start
  char* base = ws + 268435456;
  unsigned short* WpTh = (unsigned short*)(base);            // later reused as Wch
  unsigned short* WpTl = (unsigned short*)(base + 2097152);  // later reused as Wcl
  unsigned short* Whh  = (unsigned short*)(base + 4194304);
  unsigned short* Whl  = (unsigned short*)(base + 6291456);
  float*       pooled  = (float*)(base + 8388608);
  float*           bc  = (float*)(base + 8388608 + 131072);
  unsigned short* Wch  = WpTh;  // WpT dead after Wc GEMM
  unsigned short* Wcl  = WpTl;

  // Small-weight preprocessing
  transpose_split<<<dim3(32, 32), 256, 0, stream>>>(W_proj, WpTh, WpTl);
  split_kernel<<<(int)(nW / 4 / 256), 256, 0, stream>>>(W_hid, Whh, Whl, (int)(nW / 4));
  bias_combine<<<1024, 64, 0, stream>>>(W_hid, b_proj, b_hid, bc);
  // Wc[g,d] = sum_h Wh[g,h] * WpT[d,h]
  gemm_bt_split<<<64, 256, 0, stream>>>(Whh, Whl, WpTh, WpTl, nullptr, Wc, 1024);
  split_kernel<<<(int)(nW / 4 / 256), 256, 0, stream>>>(Wc, Wch, Wcl, (int)(nW / 4));

  // Main path
  split_kernel<<<(int)(nX / 4 / 256), 256, 0, stream>>>(x, Xh, Xl, (int)(nX / 4));
  gemm_bt_split<<<2048, 256, 0, stream>>>(Xh, Xl, Wch, Wcl, bc, Y2, M);

  lif_part_kernel<<<1024, 256, 0, stream>>>(Y2, part);
  pool_reduce<<<128, 256, 0, stream>>>(part, pooled);
  head_kernel<<<320, 64, 0, stream>>>(pooled, W_out, b_out, out);
}